// Round 2
// 339.114 us; speedup vs baseline: 1.0102x; 1.0102x over previous
//
#include <hip/hip_runtime.h>
#include <hip/hip_bf16.h>

// Round 10 (= round 9 resubmit; prior run died to container-acquire failure,
// no counters). Attention inner loop on 32x32x16 MFMA with fully in-register
// softmax (T12): S^T = K*Q^T so each lane owns one query column; P packed to
// bf16 via v_cvt_pk_bf16_f32 and redistributed across half-waves with
// permlane32_swap directly into the PV A-fragment layout. Deletes the P LDS
// round-trip (plds, lgkmcnt serialization, 5.4M bank-conflict cyc) and ~60%
// of per-step VALU. MFMAs per 32x32 key-step: 18 -> 8.
// Hardening vs round 9: launch_bounds(256,3) (VGPR cap 168, no forced spill;
// est. footprint ~140) and builtin permlane32_swap with asm fallback.
// GEMMs + cast + queue/merge structure frozen (round-8 known-good).
// ws: [8 counters @128B = 1KB] | xb[8M] | wab[3M] | wpb[1M] | Q[8M] | K[8M] | Vt[8M] | O[8M]

typedef __hip_bfloat16 bf16;
typedef __attribute__((ext_vector_type(8))) short bf16x8;   // 8 bf16 / 4 VGPRs
typedef __attribute__((ext_vector_type(4))) float f32x4;
typedef __attribute__((ext_vector_type(16))) float f32x16;

#define MFMA16(a, b, c) __builtin_amdgcn_mfma_f32_16x16x32_bf16(a, b, c, 0, 0, 0)
#define MFMA32(a, b, c) __builtin_amdgcn_mfma_f32_32x32x16_bf16(a, b, c, 0, 0, 0)
#define GLOAD_LDS(g, l) __builtin_amdgcn_global_load_lds( \
    (const __attribute__((address_space(1))) void*)(g),    \
    (__attribute__((address_space(3))) void*)(l), 16, 0, 0)

constexpr int Bn = 4, Tn = 2048, Cn = 1024, Hn = 16, Dn = 64;
constexpr size_t HT_ELEMS = (size_t)64 * Tn * Dn;   // 8388608
constexpr float QSCALE = 0.18033688011112042f;      // 0.125 * log2(e)
constexpr int OSTRIDE = 36;                         // obuf row stride (floats)

__device__ __forceinline__ short f2bf(float f) {    // RNE fp32->bf16 (finite)
    unsigned u = __float_as_uint(f);
    return (short)((u + 0x7FFF + ((u >> 16) & 1)) >> 16);
}
__device__ __forceinline__ bf16 bfbits(short s) { bf16 b; __builtin_memcpy(&b, &s, 2); return b; }

__device__ __forceinline__ unsigned cvtpk_bf16(float lo, float hi) {
    unsigned r;
    asm("v_cvt_pk_bf16_f32 %0, %1, %2" : "=v"(r) : "v"(lo), "v"(hi));
    return r;
}
// swap(a,b): a' = {a_lo, b_lo}, b' = {a_hi, b_hi}  (32-lane halves)
__device__ __forceinline__ void permswap(unsigned& a, unsigned& b) {
#if __has_builtin(__builtin_amdgcn_permlane32_swap)
    auto r = __builtin_amdgcn_permlane32_swap(a, b, false, false);
    a = (unsigned)r[0]; b = (unsigned)r[1];
#else
    asm("v_permlane32_swap_b32 %0, %1" : "+v"(a), "+v"(b));
#endif
}
__device__ __forceinline__ bf16x8 pack4(unsigned w0, unsigned w1, unsigned w2, unsigned w3) {
    union { unsigned u[4]; bf16x8 v; } t;
    t.u[0] = w0; t.u[1] = w1; t.u[2] = w2; t.u[3] = w3;
    return t.v;
}

// ---------------- fp32 -> bf16 cast, all three inputs in one launch -------
// Output region xb|wab|wpb is contiguous; segment-select the input.
// Units of 8 elems: x 1048576 | w_attn 393216 | w_proj 131072 (total 1572864).
__global__ __launch_bounds__(256) void cast3_kernel(
    const float* __restrict__ x, const float* __restrict__ wa,
    const float* __restrict__ wp, bf16* __restrict__ out)
{
    size_t i = (size_t)blockIdx.x * 256 + threadIdx.x;
    const float* src; size_t off;
    if (i < 1048576)      { src = x;  off = i; }
    else if (i < 1441792) { src = wa; off = i - 1048576; }
    else                  { src = wp; off = i - 1441792; }
    const float4* p = (const float4*)(src + off * 8);
    float4 a = p[0], b = p[1];
    bf16x8 r;
    r[0] = f2bf(a.x); r[1] = f2bf(a.y); r[2] = f2bf(a.z); r[3] = f2bf(a.w);
    r[4] = f2bf(b.x); r[5] = f2bf(b.y); r[6] = f2bf(b.z); r[7] = f2bf(b.w);
    *(bf16x8*)(out + i * 8) = r;
}

// ---------------- QKV GEMM: 128x128 tile, LDS-staged (m97 pattern) --------
__global__ __launch_bounds__(256) void qkv_gemm128(
    const bf16* __restrict__ Am, const bf16* __restrict__ Wm,
    const float* __restrict__ bias,
    bf16* __restrict__ qo, bf16* __restrict__ ko, bf16* __restrict__ vo)
{
    constexpr int K = 1024;
    __shared__ bf16 As[4096], Bs[4096];          // 128 rows x 32 k, stride 32
    const int tid = threadIdx.x;
    const int lane = tid & 63, w = tid >> 6;
    const int row = lane & 15, quad = lane >> 4;
    const int tn = blockIdx.x % 24, tm = blockIdx.x / 24;
    const int m0 = tm * 128, n0 = tn * 128;

    const int srow = tid >> 2, skch = tid & 3;   // staging: 4 threads/row (64B)
    const bf16* ag0 = Am + (size_t)(m0 + srow) * K + skch * 8;
    const bf16* ag1 = ag0 + (size_t)64 * K;
    const bf16* wg0 = Wm + (size_t)(n0 + srow) * K + skch * 8;
    const bf16* wg1 = wg0 + (size_t)64 * K;
    bf16* asl0 = As + tid * 8;  bf16* asl1 = As + 2048 + tid * 8;
    bf16* bsl0 = Bs + tid * 8;  bf16* bsl1 = Bs + 2048 + tid * 8;

    f32x4 acc[4][4];
    #pragma unroll
    for (int i = 0; i < 4; i++)
        #pragma unroll
        for (int j = 0; j < 4; j++) acc[i][j] = {0, 0, 0, 0};

    const int r0 = (w >> 1) * 64, c0 = (w & 1) * 64;

    for (int k0 = 0; k0 < K; k0 += 32) {
        __syncthreads();
        GLOAD_LDS(ag0 + k0, asl0);
        GLOAD_LDS(ag1 + k0, asl1);
        GLOAD_LDS(wg0 + k0, bsl0);
        GLOAD_LDS(wg1 + k0, bsl1);
        __syncthreads();
        bf16x8 af[4], bfv[4];
        #pragma unroll
        for (int it = 0; it < 4; it++)
            af[it] = *(const bf16x8*)(As + (r0 + it * 16 + row) * 32 + quad * 8);
        #pragma unroll
        for (int jt = 0; jt < 4; jt++)
            bfv[jt] = *(const bf16x8*)(Bs + (c0 + jt * 16 + row) * 32 + quad * 8);
        #pragma unroll
        for (int it = 0; it < 4; it++)
            #pragma unroll
            for (int jt = 0; jt < 4; jt++)
                acc[it][jt] = MFMA16(af[it], bfv[jt], acc[it][jt]);
    }

    #pragma unroll
    for (int it = 0; it < 4; it++)
    #pragma unroll
    for (int jt = 0; jt < 4; jt++)
    #pragma unroll
    for (int r = 0; r < 4; r++) {
        int m = m0 + r0 + it * 16 + quad * 4 + r;
        int n = n0 + c0 + jt * 16 + row;
        float val = acc[it][jt][r] + bias[n];
        int which = n >> 10, cc = n & 1023;
        if (which == 0) val *= QSCALE;
        bf16 bv = bfbits(f2bf(val));
        int h = cc >> 6, d = cc & 63;
        int b = m >> 11, t = m & 2047;
        int bh = b * Hn + h;
        if (which == 0)      qo[((size_t)bh * Tn + t) * Dn + d] = bv;
        else if (which == 1) ko[((size_t)bh * Tn + t) * Dn + d] = bv;
        else                 vo[((size_t)bh * Dn + d) * Tn + t] = bv;
    }
}

// ---------------- Attention: per-XCD queue + block-level k-split ----------
// Item = (bh, 32-query tile). Block's 4 waves split key-blocks j=w,w+4,...
// Per j-step (32 keys x 32 queries), all in registers:
//   S^T = K*Q^T via 4x mfma_32x32x16 (rows=keys, cols=queries, lane owns
//   query l31); exp2 -> p[16] f32; lsum = f32 add-tree; P packed to bf16 via
//   v_cvt_pk_bf16_f32 and half-wave-swapped via permlane32_swap, which lands
//   exactly in the 32x32x16 A-operand layout; PV = 4x mfma_32x32x16.
// Partial (o2,lsum) merged across waves via LDS obuf/lbuf as before.
__global__ __launch_bounds__(256, 3) void attn_kernel(
    const bf16* __restrict__ qb, const bf16* __restrict__ kb,
    const bf16* __restrict__ vtb, bf16* __restrict__ ob,
    unsigned* __restrict__ counters)
{
    __shared__ float obuf[64][OSTRIDE];         // 9 KB: merge buffer [d][q]
    __shared__ float lbuf[32];
    __shared__ unsigned item_s;
    const int tid  = threadIdx.x;
    const int lane = tid & 63;
    const int w    = tid >> 6;
    const int l31  = lane & 31, hl = lane >> 5;
    const int qid = blockIdx.x & 7;             // round-robin XCD heuristic
    unsigned* ctr = counters + qid * 32;        // 128B apart

    for (;;) {
        if (tid == 0) item_s = atomicAdd(ctr, 1u);
        __syncthreads();
        const unsigned item = item_s;
        if (item >= 512u) break;
        const int qt = 63 - (int)(item >> 3);   // LPT: longest first
        const int bh = qid * 8 + (int)(item & 7);
        const int q0 = qt * 32;

        const bf16* Q  = qb  + (size_t)bh * Tn * Dn;
        const bf16* Kp = kb  + (size_t)bh * Tn * Dn;
        const bf16* Vt = vtb + (size_t)bh * Dn * Tn;

        // Q fragments: B-operand of S^T, B[k=d][col=query l31]
        bf16x8 bQ[4];
        {
            const bf16* qp = Q + (size_t)(q0 + l31) * Dn + hl * 8;
            #pragma unroll
            for (int kf = 0; kf < 4; kf++) bQ[kf] = *(const bf16x8*)(qp + kf * 16);
        }

        f32x16 o2[2];
        o2[0] = {0,0,0,0,0,0,0,0,0,0,0,0,0,0,0,0};
        o2[1] = {0,0,0,0,0,0,0,0,0,0,0,0,0,0,0,0};
        float lsum = 0.f;

        // this wave's key-blocks: j = w, w+4, ... <= qt
        for (int j = w; j <= qt; j += 4) {
            const int k0 = j * 32;
            bf16x8 aK[4], vf[4];
            const bf16* kp = Kp + (size_t)(k0 + l31) * Dn + hl * 8;
            #pragma unroll
            for (int kf = 0; kf < 4; kf++) aK[kf] = *(const bf16x8*)(kp + kf * 16);
            const bf16* vp = Vt + (size_t)l31 * Tn + k0 + hl * 8;
            vf[0] = *(const bf16x8*)(vp);
            vf[1] = *(const bf16x8*)(vp + 16);
            vf[2] = *(const bf16x8*)(vp + (size_t)32 * Tn);
            vf[3] = *(const bf16x8*)(vp + (size_t)32 * Tn + 16);

            // S^T[key][query]: row = (r&3)+8*(r>>2)+4*hl, col = l31
            f32x16 s = {0,0,0,0,0,0,0,0,0,0,0,0,0,0,0,0};
            __builtin_amdgcn_s_setprio(1);
            #pragma unroll
            for (int kf = 0; kf < 4; kf++) s = MFMA32(aK[kf], bQ[kf], s);
            __builtin_amdgcn_s_setprio(0);

            float p[16];
            if (j == qt) {                       // diagonal block: causal mask
                #pragma unroll
                for (int r = 0; r < 16; r++) {
                    const int krow = (r & 3) + 8 * (r >> 2) + 4 * hl;
                    float e = exp2f(s[r]);
                    p[r] = (krow > l31) ? 0.f : e;
                }
            } else {
                #pragma unroll
                for (int r = 0; r < 16; r++) p[r] = exp2f(s[r]);
            }
            lsum += (((p[0]+p[1]) + (p[2]+p[3])) + ((p[4]+p[5]) + (p[6]+p[7])))
                  + (((p[8]+p[9]) + (p[10]+p[11])) + ((p[12]+p[13]) + (p[14]+p[15])));

            // pack P -> bf16 pairs, swap half-waves into A-operand layout
            unsigned a0 = cvtpk_bf16(p[0],  p[1]),  b0 = cvtpk_bf16(p[4],  p[5]);
            unsigned a1 = cvtpk_bf16(p[2],  p[3]),  b1 = cvtpk_bf16(p[6],  p[7]);
            unsigned a2 = cvtpk_bf16(p[8],  p[9]),  b2 = cvtpk_bf16(p[12], p[13]);
            unsigned a3 = cvtpk_bf16(p[10], p[11]), b3 = cvtpk_bf16(p[14], p[15]);
            permswap(a0, b0);
            permswap(a1, b1);
            permswap(a2, b2);
            permswap(a3, b3);
            const bf16x8 P0 = pack4(a0, a1, b0, b1);   // keys 0..15
            const bf16x8 P1 = pack4(a2, a3, b2, b3);   // keys 16..31

            __builtin_amdgcn_s_setprio(1);
            o2[0] = MFMA32(P0, vf[0], o2[0]);
            o2[0] = MFMA32(P1, vf[1], o2[0]);
            o2[1] = MFMA32(P0, vf[2], o2[1]);
            o2[1] = MFMA32(P1, vf[3], o2[1]);
            __builtin_amdgcn_s_setprio(0);
        }

        // lsum partner-sum across hl halves (all lanes end with full q-sum)
        unsigned lsu = __float_as_uint(lsum), lsv = lsu;
        permswap(lsu, lsv);
        const float ltot = __uint_as_float(lsu) + __uint_as_float(lsv);

        // ---- merge partials: obuf[d][q] (+ lbuf[q]), waves 3->0 ----
        __syncthreads();
        #pragma unroll
        for (int ww = 3; ww >= 0; ww--) {
            if (w == ww) {
                #pragma unroll
                for (int nt = 0; nt < 2; nt++)
                    #pragma unroll
                    for (int g = 0; g < 4; g++) {
                        // o2[nt][g*4+rr]: query = rr + 8*g + 4*hl, d = nt*32+l31
                        float* dst = &obuf[nt * 32 + l31][g * 8 + hl * 4];
                        f32x4 vv = { o2[nt][g*4+0], o2[nt][g*4+1],
                                     o2[nt][g*4+2], o2[nt][g*4+3] };
                        if (ww != 3) { f32x4 old = *(f32x4*)dst; vv += old; }
                        *(f32x4*)dst = vv;
                    }
                if (hl == 0) {
                    if (ww == 3) lbuf[l31] = ltot;
                    else         lbuf[l31] += ltot;
                }
            }
            __syncthreads();
        }

        // ---- final write: 256 threads, 8 d-elems each ----
        {
            const int q = tid >> 3, dblk = (tid & 7) * 8;
            const float rcp = 1.0f / lbuf[q];
            bf16x8 rv;
            #pragma unroll
            for (int d = 0; d < 8; d++)
                rv[d] = f2bf(obuf[dblk + d][q] * rcp);
            const int b = bh >> 4, h = bh & 15;
            const int t = q0 + q;
            *(bf16x8*)(ob + ((size_t)(b * Tn + t)) * Cn + h * Dn + dblk) = rv;
        }
        __syncthreads();   // obuf/lbuf/item_s reuse guard
    }
}

// ---------------- Output projection: 128x128 tile, fp32 out ---------------
__global__ __launch_bounds__(256) void proj_gemm128(
    const bf16* __restrict__ Am, const bf16* __restrict__ Wm,
    const float* __restrict__ bias, float* __restrict__ out)
{
    constexpr int K = 1024;
    __shared__ bf16 As[4096], Bs[4096];
    const int tid = threadIdx.x;
    const int lane = tid & 63, w = tid >> 6;
    const int row = lane & 15, quad = lane >> 4;
    const int tn = blockIdx.x % 8, tm = blockIdx.x / 8;
    const int m0 = tm * 128, n0 = tn * 128;

    const int srow = tid >> 2, skch = tid & 3;
    const bf16* ag0 = Am + (size_t)(m0 + srow) * K + skch * 8;
    const bf16* ag1 = ag0 + (size_t)64 * K;
    const bf16* wg0 = Wm + (size_t)(n0 + srow) * K + skch * 8;
    const bf16* wg1 = wg0 + (size_t)64 * K;
    bf16* asl0 = As + tid * 8;  bf16* asl1 = As + 2048 + tid * 8;
    bf16* bsl0 = Bs + tid * 8;  bf16* bsl1 = Bs + 2048 + tid * 8;

    f32x4 acc[4][4];
    #pragma unroll
    for (int i = 0; i < 4; i++)
        #pragma unroll
        for (int j = 0; j < 4; j++) acc[i][j] = {0, 0, 0, 0};

    const int r0 = (w >> 1) * 64, c0 = (w & 1) * 64;

    for (int k0 = 0; k0 < K; k0 += 32) {
        __syncthreads();
        GLOAD_LDS(ag0 + k0, asl0);
        GLOAD_LDS(ag1 + k0, asl1);
        GLOAD_LDS(wg0 + k0, bsl0);
        GLOAD_LDS(wg1 + k0, bsl1);
        __syncthreads();
        bf16x8 af[4], bfv[4];
        #pragma unroll
        for (int it = 0; it < 4; it++)
            af[it] = *(const bf16x8*)(As + (r0 + it * 16 + row) * 32 + quad * 8);
        #pragma unroll
        for (int jt = 0; jt < 4; jt++)
            bfv[jt] = *(const bf16x8*)(Bs + (c0 + jt * 16 + row) * 32 + quad * 8);
        #pragma unroll
        for (int it = 0; it < 4; it++)
            #pragma unroll
            for (int jt = 0; jt < 4; jt++)
                acc[it][jt] = MFMA16(af[it], bfv[jt], acc[it][jt]);
    }

    #pragma unroll
    for (int it = 0; it < 4; it++)
    #pragma unroll
    for (int jt = 0; jt < 4; jt++)
    #pragma unroll
    for (int r = 0; r < 4; r++) {
        int m = m0 + r0 + it * 16 + quad * 4 + r;
        int n = n0 + c0 + jt * 16 + row;
        out[(size_t)m * 1024 + n] = acc[it][jt][r] + bias[n];
    }
}

extern "C" void kernel_launch(void* const* d_in, const int* in_sizes, int n_in,
                              void* d_out, int out_size, void* d_ws, size_t ws_size,
                              hipStream_t stream) {
    const float* x      = (const float*)d_in[0];
    const float* w_attn = (const float*)d_in[1];
    const float* b_attn = (const float*)d_in[2];
    const float* w_proj = (const float*)d_in[3];
    const float* b_proj = (const float*)d_in[4];
    float* out = (float*)d_out;

    unsigned* counters = (unsigned*)d_ws;             // 8 counters @128B
    bf16* ws  = (bf16*)((char*)d_ws + 1024);
    bf16* xb  = ws;                                   // 8M elems
    bf16* wab = xb  + (size_t)8192 * 1024;            // 3M (contiguous after xb)
    bf16* wpb = wab + (size_t)3072 * 1024;            // 1M (contiguous after wab)
    bf16* q   = wpb + (size_t)1024 * 1024;            // 8M
    bf16* k   = q  + HT_ELEMS;
    bf16* vt  = k  + HT_ELEMS;
    bf16* o   = vt + HT_ELEMS;

    hipMemsetAsync(counters, 0, 1024, stream);

    cast3_kernel<<<6144, 256, 0, stream>>>(x, w_attn, w_proj, xb);

    qkv_gemm128 <<<64 * 24, 256, 0, stream>>>(xb, wab, b_attn, q, k, vt);
    attn_kernel <<<2048, 256, 0, stream>>>(q, k, vt, o, counters);
    proj_gemm128<<<64 * 8, 256, 0, stream>>>(o, wpb, b_proj, out);
}